// Round 1
// baseline (130.386 us; speedup 1.0000x reference)
//
#include <hip/hip_runtime.h>

#define LEVEL 256
#define BLOCKS 8
// B=16, H=W=1024, bm=bn=128, tv = 16384/256*10 = 640

// ---------------------------------------------------------------------------
// Kernel 1: per-image-block histogram -> clip -> cdf -> u8 map table.
// Also stages the pixel values as uint8 into ws so kernel 2 reads 16 MB
// instead of 64 MB.
// grid = 16*8*8 = 1024 blocks, 256 threads each.
// maps8 layout in ws: uint8 maps8[16][8][8][256]  (256 KB total)
// ---------------------------------------------------------------------------
__global__ __launch_bounds__(256) void clahe_hist_kernel(const float* __restrict__ img,
                                                         unsigned char* __restrict__ maps8,
                                                         unsigned char* __restrict__ u8img) {
    __shared__ int   hist[256];
    __shared__ float red[256];
    __shared__ float scan[256];
    __shared__ float s_me;

    const int t   = threadIdx.x;
    const int bid = blockIdx.x;            // 0..1023
    const int b   = bid >> 6;              // image
    const int blk = bid & 63;
    const int br  = blk >> 3;
    const int bc  = blk & 7;

    hist[t] = 0;
    __syncthreads();

    // 128x128 block = 4096 float4 loads, 16 per thread, coalesced
    const size_t base = (size_t)b * 1048576 + (size_t)(br * 128) * 1024 + (size_t)(bc * 128);
    const float* p = img + base;
    unsigned char* q8 = u8img ? (u8img + base) : nullptr;
    for (int it = 0; it < 16; ++it) {
        int idx = it * 256 + t;            // 0..4095
        int y   = idx >> 5;                // 0..127
        int x   = (idx & 31) * 4;          // 0..124
        float4 v = *(const float4*)(p + (size_t)y * 1024 + x);
        int va = (int)v.x, vb = (int)v.y, vc = (int)v.z, vd = (int)v.w;
        atomicAdd(&hist[va], 1);
        atomicAdd(&hist[vb], 1);
        atomicAdd(&hist[vc], 1);
        atomicAdd(&hist[vd], 1);
        if (q8) {
            uchar4 pk;
            pk.x = (unsigned char)va; pk.y = (unsigned char)vb;
            pk.z = (unsigned char)vc; pk.w = (unsigned char)vd;
            *(uchar4*)(q8 + (size_t)y * 1024 + x) = pk;
        }
    }
    __syncthreads();

    // clip: tv = 640, redistribute excess uniformly (all integer-exact in fp32)
    const float tv = 640.0f;
    float h = (float)hist[t];
    float extra = fmaxf(h - tv, 0.0f);
    red[t] = extra;
    __syncthreads();
    for (int off = 128; off > 0; off >>= 1) {
        if (t < off) red[t] += red[t + off];
        __syncthreads();
    }
    if (t == 0) s_me = red[0] * (1.0f / 256.0f);   // exact: /2^8
    __syncthreads();
    const float me = s_me;
    float clip = floorf(((h >= tv) ? tv : h) + me);

    // inclusive scan over 256 bins (integer-valued -> exact any order)
    scan[t] = clip;
    __syncthreads();
    for (int off = 1; off < 256; off <<= 1) {
        float add = (t >= off) ? scan[t - off] : 0.0f;
        __syncthreads();
        scan[t] += add;
        __syncthreads();
    }
    float cdf = scan[t] * (255.0f / 16384.0f);     // exact scale: 255/2^14
    int m = ((int)floorf(cdf)) & 255;
    maps8[(size_t)bid * 256 + t] = (unsigned char)m;   // exact 0..255
}

// ---------------------------------------------------------------------------
// Kernel 2: per-pixel bilinear blend of 4 neighboring block maps.
// 64x128 pixel tile per workgroup. r is constant over the 64 rows; the 128
// columns span two interpolation quadrants (c changes at 64-aligned
// boundaries), handled with TWO packed LDS tables.
// Each table packs the 4 needed maps as bytes into one u32 per bin:
//   random lookup = ds_read_b32 spread over all 32 banks (~2 lanes/bank,
//   free) instead of the old float4 ds_read_b128 crowding 8 bank groups.
// u8 image read as uint4 (16 px): every global load is a full aligned 128 B
// line -> zero sector overfetch.
// grid = (8, 16, 16) = (W/128, H/64, B), 256 threads, 2 iters x 16 px.
// ---------------------------------------------------------------------------
template <bool U8>
__global__ __launch_bounds__(256) void clahe_map_kernel(const float* __restrict__ imgf,
                                                        const unsigned char* __restrict__ img8,
                                                        const unsigned char* __restrict__ maps8,
                                                        float* __restrict__ out) {
#pragma clang fp contract(off)
    __shared__ unsigned int mL[256];   // packed {lu,lb,ru,rb} for left  64 cols
    __shared__ unsigned int mR[256];   // packed {lu,lb,ru,rb} for right 64 cols

    const int t  = threadIdx.x;
    const int b  = blockIdx.z;
    const int i0 = blockIdx.y * 64;
    const int j0 = blockIdx.x * 128;

    // r = trunc((i-64)/128) toward zero, constant over the 64-row tile
    const int r  = (i0 >= 64) ? ((i0 - 64) >> 7) : 0;
    const int rp = min(r + 1, BLOCKS - 1);
    const bool rEdge = (r >= BLOCKS - 1);

    // column quadrants: left half [j0, j0+64), right half [j0+64, j0+128)
    const int cL  = (j0 >= 64) ? ((j0 - 64) >> 7) : 0;
    const int cR  = j0 >> 7;
    const int cLp = min(cL + 1, BLOCKS - 1);
    const int cRp = min(cR + 1, BLOCKS - 1);
    const bool cLEdge = (cL >= BLOCKS - 1);
    const bool cREdge = (cR >= BLOCKS - 1);

    const unsigned char* mb = maps8 + (size_t)b * 64 * 256;
    {
        unsigned lu = mb[(r  * 8 + cL ) * 256 + t];
        unsigned lb = mb[(rp * 8 + cL ) * 256 + t];
        unsigned ru = mb[(r  * 8 + cLp) * 256 + t];
        unsigned rb = mb[(rp * 8 + cLp) * 256 + t];
        mL[t] = lu | (lb << 8) | (ru << 16) | (rb << 24);
        unsigned lu2 = mb[(r  * 8 + cR ) * 256 + t];
        unsigned lb2 = mb[(rp * 8 + cR ) * 256 + t];
        unsigned ru2 = mb[(r  * 8 + cRp) * 256 + t];
        unsigned rb2 = mb[(rp * 8 + cRp) * 256 + t];
        mR[t] = lu2 | (lb2 << 8) | (ru2 << 16) | (rb2 << 24);
    }
    __syncthreads();

    const size_t ibase = (size_t)b * 1048576;
    const float rbase = (float)(r * 128 + 64);
    const float cbaseL = (float)(cL * 128 + 64);
    const float cbaseR = (float)(cR * 128 + 64);

#pragma unroll
    for (int it = 0; it < 2; ++it) {
        const int idx = it * 256 + t;      // 0..511
        const int row = idx >> 3;          // 0..63
        const int cu  = (idx & 7) * 16;    // 0..112, 16-px chunk
        const int i   = i0 + row;
        const int j   = j0 + cu;
        const int half = cu >> 6;          // chunk never crosses the 64 split
        const unsigned int* mt = half ? mR : mL;
        const bool  cE    = half ? cREdge : cLEdge;
        const float cbase = half ? cbaseR : cbaseL;

        unsigned int w[4];                 // 16 pixel values, 4 per u32
        if (U8) {
            uint4 px = *(const uint4*)(img8 + ibase + (size_t)i * 1024 + j);
            w[0] = px.x; w[1] = px.y; w[2] = px.z; w[3] = px.w;
        } else {
            const float* pf = imgf + ibase + (size_t)i * 1024 + j;
#pragma unroll
            for (int q = 0; q < 4; ++q) {
                float4 f = *(const float4*)(pf + q * 4);
                w[q] = (((unsigned)(int)f.x) & 255u)
                     | ((((unsigned)(int)f.y) & 255u) << 8)
                     | ((((unsigned)(int)f.z) & 255u) << 16)
                     | ((((unsigned)(int)f.w) & 255u) << 24);
            }
        }

        const float x1 = rEdge ? 0.0f : ((float)i - rbase) * 0.0078125f;
        const float x0 = 1.0f - x1;

        float o16[16];
#pragma unroll
        for (int q = 0; q < 4; ++q) {
            const unsigned int wq = w[q];
#pragma unroll
            for (int k = 0; k < 4; ++k) {
                const int v = (wq >> (8 * k)) & 255;
                const unsigned m = mt[v];
                // exact integers 0..255 -> v_cvt_f32_ubyte{0..3}
                const float lu = (float)(m & 255u);
                const float lb = (float)((m >> 8) & 255u);
                const float ru = (float)((m >> 16) & 255u);
                const float rb = (float)(m >> 24);
                const float jj = (float)(j + q * 4 + k);
                const float y1 = cE ? 0.0f : (jj - cbase) * 0.0078125f;
                // exact expression order of the reference; no FMA contraction
                float o = (1.0f - y1) * (x0 * lu + x1 * lb)
                        + y1 * (x0 * ru + x1 * rb);
                // trunc toward zero then floor-mod 256 (two's-complement & 255)
                o16[q * 4 + k] = (float)(((int)o) & 255);
            }
        }

        float* po = out + ibase + (size_t)i * 1024 + j;
        *(float4*)(po +  0) = make_float4(o16[ 0], o16[ 1], o16[ 2], o16[ 3]);
        *(float4*)(po +  4) = make_float4(o16[ 4], o16[ 5], o16[ 6], o16[ 7]);
        *(float4*)(po +  8) = make_float4(o16[ 8], o16[ 9], o16[10], o16[11]);
        *(float4*)(po + 12) = make_float4(o16[12], o16[13], o16[14], o16[15]);
    }
}

extern "C" void kernel_launch(void* const* d_in, const int* in_sizes, int n_in,
                              void* d_out, int out_size, void* d_ws, size_t ws_size,
                              hipStream_t stream) {
    const float* img = (const float*)d_in[0];
    float* out = (float*)d_out;

    unsigned char* maps8 = (unsigned char*)d_ws;            // 256 KB
    const size_t maps_bytes = (size_t)1024 * 256;           // 16*64*256 u8
    const size_t u8_bytes   = (size_t)16 * 1024 * 1024;
    const bool use_u8 = ws_size >= maps_bytes + u8_bytes;
    unsigned char* u8img = use_u8 ? ((unsigned char*)d_ws + maps_bytes) : nullptr;

    clahe_hist_kernel<<<dim3(1024), dim3(256), 0, stream>>>(img, maps8, u8img);
    if (use_u8) {
        clahe_map_kernel<true><<<dim3(8, 16, 16), dim3(256), 0, stream>>>(
            nullptr, u8img, maps8, out);
    } else {
        clahe_map_kernel<false><<<dim3(8, 16, 16), dim3(256), 0, stream>>>(
            img, nullptr, maps8, out);
    }
}